// Round 13
// baseline (3456.690 us; speedup 1.0000x reference)
//
#include <hip/hip_runtime.h>

// Round 19: take B off the LDS pipe. r16/r17/r18 proved the toolchain hard-
// caps this kernel at 128 VGPR (spills acc[16][8] rather than drop below
// 4 waves/SIMD) -> 16x8 tile abandoned. Within <=128 VGPR, the 67% VALUBusy
// pin (r13/14/15, schedule-invariant) is modeled as LDS-pipe oversubscription:
// 4 ds_read_b128/k-step/wave (2A+2B ~48 pipe cyc) vs 128 VALU cyc, x4 SIMDs
// sharing one LDS -> demand 1.5x.
// Change: read B fragments DIRECTLY from global (B's [k][n] layout already
// matches the fragment pattern: contiguous 16B/lane, wave-coalesced,
// L2/L3-resident re-reads). LDS keeps only A (transpose needed): 2 b128/
// k-step/wave -> LDS demand ~0.8 -> VALU-bound. B staging regs/writes/LDS
// gone: VGPR ~110-125 (fits 128 clean), LDS 16.9KB, grid 16x16x4=1024 =
// 4 blocks/CU. Bit-exact: same B bits, same serial k-ascending FMA chain,
// same 512-k chunks + ordered reduce -> absmax 0.0.
// Tripwires: WRITE_SIZE must be 65536 KB (no spill); FETCH may rise
// (L3-absorbed B re-reads) but hbm_pct_peak must stay <25%.

#define NMAT 2048

constexpr int FM = 128, FN = 128, FK = 16; // 256 threads, 8x8 out/thread
constexpr int LDA = FM + 4;                // 132 floats: 16B-multiple rows
constexpr int KCHUNK = 512;                // flush granularity (bit-exact)

// ---------- split-K chunk kernel: acc over k in [z*512, (z+1)*512) ----------
__global__ __launch_bounds__(256) void sgemm_chunk(
    const float* __restrict__ Am, const float* __restrict__ Bm,
    float* __restrict__ Pm) {
  __shared__ float As[2][FK][LDA]; // [buf][k][m] — A only, 16896 B
  const int tid = threadIdx.x;
  const int row0 = blockIdx.y * FM;
  const int col0 = blockIdx.x * FN;
  const int kb = blockIdx.z * KCHUNK;
  const int ty = tid >> 4; // 0..15 -> rows {ty*4..+3, 64+ty*4..+3}
  const int tx = tid & 15; // 0..15 -> cols {tx*4..+3, 64+tx*4..+3}

  // A staging indices (two passes: ar, ar+64)
  const int ar = tid >> 2;      // 0..63
  const int ac = (tid & 3) * 4; // 0,4,8,12

  float acc[8][8] = {};
  float4 va0, va1;

  const float* pa0 = &Am[(size_t)(row0 + ar) * NMAT + kb + ac];
  const float* pa1 = pa0 + (size_t)64 * NMAT;
  // B fragment base: row kb of B, this thread's column quad
  const float* pbx = &Bm[(size_t)kb * NMAT + col0 + tx * 4];

  constexpr int NT = KCHUNK / FK; // 32 tiles

  // prologue: tile 0 -> buf 0
  va0 = *(const float4*)pa0;
  va1 = *(const float4*)pa1;
  As[0][ac + 0][ar] = va0.x;
  As[0][ac + 1][ar] = va0.y;
  As[0][ac + 2][ar] = va0.z;
  As[0][ac + 3][ar] = va0.w;
  As[0][ac + 0][ar + 64] = va1.x;
  As[0][ac + 1][ar + 64] = va1.y;
  As[0][ac + 2][ar + 64] = va1.z;
  As[0][ac + 3][ar + 64] = va1.w;
  // tile 1 -> registers
  pa0 += FK;
  pa1 += FK;
  va0 = *(const float4*)pa0;
  va1 = *(const float4*)pa1;
  __syncthreads();

#pragma unroll 1
  for (int t = 0; t < NT; ++t) {
    const int cur = t & 1;
    const int nxt = cur ^ 1;

    // store tile t+1 A (in regs) into the other buffer — overlaps with FMA
    if (t + 1 < NT) {
      As[nxt][ac + 0][ar] = va0.x;
      As[nxt][ac + 1][ar] = va0.y;
      As[nxt][ac + 2][ar] = va0.z;
      As[nxt][ac + 3][ar] = va0.w;
      As[nxt][ac + 0][ar + 64] = va1.x;
      As[nxt][ac + 1][ar + 64] = va1.y;
      As[nxt][ac + 2][ar + 64] = va1.z;
      As[nxt][ac + 3][ar + 64] = va1.w;
    }
    // issue A global loads for tile t+2 — latency hidden under FMA block
    if (t + 2 < NT) {
      pa0 += FK;
      pa1 += FK;
      va0 = *(const float4*)pa0;
      va1 = *(const float4*)pa1;
    }

    // compute: 16 k-steps, serial k-ascending per element (bit-exact order).
    // A fragments from LDS; B fragments DIRECT from global (L2/L3-served).
    const float* bp = pbx + (size_t)t * FK * NMAT;
#pragma unroll
    for (int k = 0; k < FK; ++k) {
      const float4 a0 = *(const float4*)&As[cur][k][ty * 4];
      const float4 a1 = *(const float4*)&As[cur][k][64 + ty * 4];
      const float4 b0 = *(const float4*)bp;
      const float4 b1 = *(const float4*)(bp + 64);
      bp += NMAT;
      const float af[8] = {a0.x, a0.y, a0.z, a0.w, a1.x, a1.y, a1.z, a1.w};
      const float bf[8] = {b0.x, b0.y, b0.z, b0.w, b1.x, b1.y, b1.z, b1.w};
#pragma unroll
      for (int i = 0; i < 8; ++i)
#pragma unroll
        for (int j = 0; j < 8; ++j)
          acc[i][j] = fmaf(af[i], bf[j], acc[i][j]);
    }
    __syncthreads(); // buf[nxt] complete; buf[cur] free for reuse
  }

  // write raw chunk accumulator to partial slab z
  float* dst = Pm + (size_t)blockIdx.z * NMAT * NMAT;
#pragma unroll
  for (int i = 0; i < 8; ++i) {
    const int r = row0 + ((i < 4) ? (ty * 4 + i) : (64 + ty * 4 + (i - 4)));
#pragma unroll
    for (int jb = 0; jb < 2; ++jb) {
      const int c = col0 + ((jb == 0) ? (tx * 4) : (64 + tx * 4));
      float4 v;
      v.x = acc[i][jb * 4 + 0];
      v.y = acc[i][jb * 4 + 1];
      v.z = acc[i][jb * 4 + 2];
      v.w = acc[i][jb * 4 + 3];
      *(float4*)&dst[(size_t)r * NMAT + c] = v;
    }
  }
}

// ordered reduction: out = (((0+c0)+c1)+c2)+c3 [+ Addm], one fp32 rounding per
// add — bit-identical to the r11 tot-flush chain + epilogue add.
template <int DO_ADD>
__global__ __launch_bounds__(256) void reduce_k4(
    const float* __restrict__ Pm, const float* __restrict__ Addm,
    float* __restrict__ outp) {
  const size_t NN = (size_t)NMAT * NMAT;
  const size_t i = ((size_t)blockIdx.x * 256 + threadIdx.x) * 4;
  const float4 c0 = *(const float4*)&Pm[i];
  const float4 c1 = *(const float4*)&Pm[i + NN];
  const float4 c2 = *(const float4*)&Pm[i + 2 * NN];
  const float4 c3 = *(const float4*)&Pm[i + 3 * NN];
  float4 v;
  v.x = __fadd_rn(__fadd_rn(__fadd_rn(__fadd_rn(0.0f, c0.x), c1.x), c2.x), c3.x);
  v.y = __fadd_rn(__fadd_rn(__fadd_rn(__fadd_rn(0.0f, c0.y), c1.y), c2.y), c3.y);
  v.z = __fadd_rn(__fadd_rn(__fadd_rn(__fadd_rn(0.0f, c0.z), c1.z), c2.z), c3.z);
  v.w = __fadd_rn(__fadd_rn(__fadd_rn(__fadd_rn(0.0f, c0.w), c1.w), c2.w), c3.w);
  if (DO_ADD) {
    const float4 ad = *(const float4*)&Addm[i];
    v.x = __fadd_rn(v.x, ad.x);
    v.y = __fadd_rn(v.y, ad.y);
    v.z = __fadd_rn(v.z, ad.z);
    v.w = __fadd_rn(v.w, ad.w);
  }
  *(float4*)&outp[i] = v;
}

// ---------- fallback: r11 full-K kernel (used only if ws too small) ----------
constexpr int LDB = FN + 4;

template <int DO_ADD>
__global__ __launch_bounds__(256) void sgemm512(
    const float* __restrict__ Am, const float* __restrict__ Bm, float* Cm,
    const float* Addm) {
  __shared__ float As[FK][LDA];
  __shared__ float Bs[FK][LDB];
  const int tid = threadIdx.x;
  const int row0 = blockIdx.y * FM;
  const int col0 = blockIdx.x * FN;
  const int ty = tid >> 4;
  const int tx = tid & 15;
  const int ar = tid >> 2;
  const int ac = (tid & 3) * 4;
  const int bk = tid >> 5;
  const int bc = (tid & 31) * 4;

  float tot[8][8] = {};
  float acc[8][8] = {};
  float4 va0, va1, vb0, vb1;

  va0 = *(const float4*)&Am[(size_t)(row0 + ar) * NMAT + ac];
  va1 = *(const float4*)&Am[(size_t)(row0 + ar + 64) * NMAT + ac];
  vb0 = *(const float4*)&Bm[(size_t)bk * NMAT + col0 + bc];
  vb1 = *(const float4*)&Bm[(size_t)(bk + 8) * NMAT + col0 + bc];

  for (int k0 = 0; k0 < NMAT; k0 += FK) {
    __syncthreads();
    As[ac + 0][ar] = va0.x;
    As[ac + 1][ar] = va0.y;
    As[ac + 2][ar] = va0.z;
    As[ac + 3][ar] = va0.w;
    As[ac + 0][ar + 64] = va1.x;
    As[ac + 1][ar + 64] = va1.y;
    As[ac + 2][ar + 64] = va1.z;
    As[ac + 3][ar + 64] = va1.w;
    *(float4*)&Bs[bk][bc] = vb0;
    *(float4*)&Bs[bk + 8][bc] = vb1;
    __syncthreads();

    if (k0 + FK < NMAT) {
      const int kn = k0 + FK;
      va0 = *(const float4*)&Am[(size_t)(row0 + ar) * NMAT + kn + ac];
      va1 = *(const float4*)&Am[(size_t)(row0 + ar + 64) * NMAT + kn + ac];
      vb0 = *(const float4*)&Bm[(size_t)(kn + bk) * NMAT + col0 + bc];
      vb1 = *(const float4*)&Bm[(size_t)(kn + bk + 8) * NMAT + col0 + bc];
    }

#pragma unroll
    for (int k = 0; k < FK; ++k) {
      const float4 a0 = *(const float4*)&As[k][ty * 4];
      const float4 a1 = *(const float4*)&As[k][64 + ty * 4];
      const float4 b0 = *(const float4*)&Bs[k][tx * 4];
      const float4 b1 = *(const float4*)&Bs[k][64 + tx * 4];
      const float af[8] = {a0.x, a0.y, a0.z, a0.w, a1.x, a1.y, a1.z, a1.w};
      const float bf[8] = {b0.x, b0.y, b0.z, b0.w, b1.x, b1.y, b1.z, b1.w};
#pragma unroll
      for (int i = 0; i < 8; ++i)
#pragma unroll
        for (int j = 0; j < 8; ++j)
          acc[i][j] = fmaf(af[i], bf[j], acc[i][j]);
    }

    if (((k0 + FK) & 511) == 0) {
#pragma unroll
      for (int i = 0; i < 8; ++i)
#pragma unroll
        for (int j = 0; j < 8; ++j) {
          tot[i][j] = __fadd_rn(tot[i][j], acc[i][j]);
          acc[i][j] = 0.0f;
        }
    }
  }

#pragma unroll
  for (int i = 0; i < 8; ++i) {
    const int r = row0 + ((i < 4) ? (ty * 4 + i) : (64 + ty * 4 + (i - 4)));
#pragma unroll
    for (int jb = 0; jb < 2; ++jb) {
      const int c = col0 + ((jb == 0) ? (tx * 4) : (64 + tx * 4));
      const size_t idx = (size_t)r * NMAT + c;
      float4 v;
      v.x = tot[i][jb * 4 + 0];
      v.y = tot[i][jb * 4 + 1];
      v.z = tot[i][jb * 4 + 2];
      v.w = tot[i][jb * 4 + 3];
      if (DO_ADD) {
        const float4 ad = *(const float4*)&Addm[idx];
        v.x = __fadd_rn(v.x, ad.x);
        v.y = __fadd_rn(v.y, ad.y);
        v.z = __fadd_rn(v.z, ad.z);
        v.w = __fadd_rn(v.w, ad.w);
      }
      *(float4*)&Cm[idx] = v;
    }
  }
}

// out = t1 - (t2 + t3*t4/t5), each op one fp32 rounding, numpy eval order.
__global__ __launch_bounds__(256) void final_fp32(
    const float* __restrict__ t1, const float* __restrict__ t2,
    const float* t3, const float* __restrict__ t4,
    const float* __restrict__ t5, float* outp) {
  size_t i = (size_t)blockIdx.x * 256 + threadIdx.x;
  float num = __fmul_rn(t3[i], t4[i]);
  float q = __fdiv_rn(num, t5[i]);
  float s = __fadd_rn(t2[i], q);
  outp[i] = __fsub_rn(t1[i], s);
}

extern "C" void kernel_launch(void* const* d_in, const int* in_sizes, int n_in,
                              void* d_out, int out_size, void* d_ws,
                              size_t ws_size, hipStream_t stream) {
  const float* X1 = (const float*)d_in[0];
  const float* X2 = (const float*)d_in[1];
  float* out = (float*)d_out;

  const size_t NN = (size_t)NMAT * NMAT;
  const size_t M32 = NN * sizeof(float); // 16 MiB
  char* w = (char*)d_ws;
  float* fA  = (float*)(w + 0 * M32);
  float* fB  = (float*)(w + 1 * M32);
  float* fC  = (float*)(w + 2 * M32);
  float* fD  = (float*)(w + 3 * M32);
  float* fP  = (float*)(w + 4 * M32);
  float* fQ  = (float*)(w + 5 * M32);
  float* t2f = (float*)(w + 6 * M32);
  float* t4f = (float*)(w + 7 * M32);
  float* fT  = (float*)(w + 2 * M32); // reuse fC slab (dead after t3)
  float* t5f = (float*)(w + 3 * M32); // reuse fD slab (dead after t4)

  dim3 blk(256);
  dim3 ew((unsigned)(NN / 256));

  if (ws_size >= 12 * M32) {
    // split-K path: 12 slabs = 192 MiB (8 named + 4 partial chunks)
    float* Pk = (float*)(w + 8 * M32); // 4 x 16 MiB partials
    dim3 gsk(NMAT / FN, NMAT / FM, 4); // 16 x 16 x 4 = 1024 blocks
    dim3 gr((unsigned)(NN / (256 * 4)));

    auto gemm = [&](const float* A, const float* B, float* dst,
                    const float* add) {
      sgemm_chunk<<<gsk, blk, 0, stream>>>(A, B, Pk);
      if (add)
        reduce_k4<1><<<gr, blk, 0, stream>>>(Pk, add, dst);
      else
        reduce_k4<0><<<gr, blk, 0, stream>>>(Pk, nullptr, dst);
    };

    gemm(X1, X1, fA, nullptr);  // A  = X1@X1
    gemm(X1, X2, fB, nullptr);  // B  = X1@X2
    gemm(X2, fB, fC, nullptr);  // C  = X2@B
    gemm(X2, fA, fD, nullptr);  // D  = X2@A
    gemm(fC, fA, fP, nullptr);  // P  = C@A
    gemm(fD, fB, fQ, nullptr);  // Q  = D@B
    gemm(fB, fA, out, fC);      // t3 = B@A + C
    gemm(fD, X2, t4f, fP);      // t4 = D@X2 + P
    gemm(fA, X2, t2f, fB);      // t2 = A@X2 + B
    gemm(fP, fA, fT, nullptr);  // T  = P@A
    gemm(fQ, fA, t5f, fT);      // t5 = Q@A + T
    final_fp32<<<ew, blk, 0, stream>>>(fA, t2f, out, t4f, t5f, out);
  } else {
    // fallback: r11 path (128 MiB ws)
    dim3 grid(NMAT / FN, NMAT / FM);
    sgemm512<0><<<grid, blk, 0, stream>>>(X1, X1, fA, nullptr);
    sgemm512<0><<<grid, blk, 0, stream>>>(X1, X2, fB, nullptr);
    sgemm512<0><<<grid, blk, 0, stream>>>(X2, fB, fC, nullptr);
    sgemm512<0><<<grid, blk, 0, stream>>>(X2, fA, fD, nullptr);
    sgemm512<0><<<grid, blk, 0, stream>>>(fC, fA, fP, nullptr);
    sgemm512<0><<<grid, blk, 0, stream>>>(fD, fB, fQ, nullptr);
    sgemm512<1><<<grid, blk, 0, stream>>>(fB, fA, out, fC);
    sgemm512<1><<<grid, blk, 0, stream>>>(fD, X2, t4f, fP);
    sgemm512<1><<<grid, blk, 0, stream>>>(fA, X2, t2f, fB);
    sgemm512<0><<<grid, blk, 0, stream>>>(fP, fA, fT, nullptr);
    sgemm512<1><<<grid, blk, 0, stream>>>(fQ, fA, t5f, fT);
    final_fp32<<<ew, blk, 0, stream>>>(fA, t2f, out, t4f, t5f, out);
  }
}

// Round 15
// 3149.286 us; speedup vs baseline: 1.0976x; 1.0976x over previous
//
#include <hip/hip_runtime.h>

// Round 20 (resubmit — container failed twice, never ran). r19 post-mortem:
// B direct from global, consumed same-k-step -> pure vmcnt latency stall
// (VALUBusy 28.7%, no spill, FETCH unchanged). The LDS-relief direction
// (A-only LDS: demand 0.75 vs 1.5 -> VALU-bound) was never reached.
// Change: bq[2][2] float4 pipeline; at global k-step g consume slot g&1,
// then load g+2 into the same slot (FK%2=0 -> slot static after unroll, no
// rule-#20 scratch). 4 loads in flight spanning 256 VALU cyc >= L2 ~200 cyc.
// Last tile peeled so the load guard is compile-time. Regs: 64 acc + 16 bq +
// 8 A-staging + frags/addr ~= 115 <= 128 cap (r19 was 76). L2 BW need
// ~20 TB/s < 34.5 ceiling; B slabs L3-resident.
// Bit-exact: identical B bits, identical serial k-ascending FMA chain,
// 512-k chunks + ordered reduce -> absmax 0.0.
// Tripwires: WRITE_SIZE = 65536 KB exactly (no spill); VALUBusy >= 78%
// (if <=50%, compiler defeated the pipeline -> revert to r13).

#define NMAT 2048

constexpr int FM = 128, FN = 128, FK = 16; // 256 threads, 8x8 out/thread
constexpr int LDA = FM + 4;                // 132 floats: 16B-multiple rows
constexpr int KCHUNK = 512;                // flush granularity (bit-exact)
constexpr int PD = 2;                      // B register-pipeline depth

// ---------- split-K chunk kernel: acc over k in [z*512, (z+1)*512) ----------
__global__ __launch_bounds__(256) void sgemm_chunk(
    const float* __restrict__ Am, const float* __restrict__ Bm,
    float* __restrict__ Pm) {
  __shared__ float As[2][FK][LDA]; // [buf][k][m] — A only, 16896 B
  const int tid = threadIdx.x;
  const int row0 = blockIdx.y * FM;
  const int col0 = blockIdx.x * FN;
  const int kb = blockIdx.z * KCHUNK;
  const int ty = tid >> 4; // 0..15 -> rows {ty*4..+3, 64+ty*4..+3}
  const int tx = tid & 15; // 0..15 -> cols {tx*4..+3, 64+tx*4..+3}

  // A staging indices (two passes: ar, ar+64)
  const int ar = tid >> 2;      // 0..63
  const int ac = (tid & 3) * 4; // 0,4,8,12

  float acc[8][8] = {};
  float4 va0, va1;
  float4 bq[PD][2]; // B fragment pipeline: slot g&1 holds k-step g

  const float* pa0 = &Am[(size_t)(row0 + ar) * NMAT + kb + ac];
  const float* pa1 = pa0 + (size_t)64 * NMAT;
  const float* pb = &Bm[(size_t)kb * NMAT + col0 + tx * 4];

  constexpr int NT = KCHUNK / FK; // 32 tiles

  // prologue: A tile 0 -> buf 0
  va0 = *(const float4*)pa0;
  va1 = *(const float4*)pa1;
  As[0][ac + 0][ar] = va0.x;
  As[0][ac + 1][ar] = va0.y;
  As[0][ac + 2][ar] = va0.z;
  As[0][ac + 3][ar] = va0.w;
  As[0][ac + 0][ar + 64] = va1.x;
  As[0][ac + 1][ar + 64] = va1.y;
  As[0][ac + 2][ar + 64] = va1.z;
  As[0][ac + 3][ar + 64] = va1.w;
  // A tile 1 -> registers
  pa0 += FK;
  pa1 += FK;
  va0 = *(const float4*)pa0;
  va1 = *(const float4*)pa1;
  // B pipeline preload: g = 0..PD-1
#pragma unroll
  for (int g = 0; g < PD; ++g) {
    bq[g][0] = *(const float4*)pb;
    bq[g][1] = *(const float4*)(pb + 64);
    pb += NMAT;
  } // pb now at g = PD
  __syncthreads();

  // main tiles t = 0 .. NT-2 (B loads unconditional; last tile peeled)
#pragma unroll 1
  for (int t = 0; t < NT - 1; ++t) {
    const int cur = t & 1;
    const int nxt = cur ^ 1;

    // store A tile t+1 (in regs) into the other buffer — overlaps with FMA
    As[nxt][ac + 0][ar] = va0.x;
    As[nxt][ac + 1][ar] = va0.y;
    As[nxt][ac + 2][ar] = va0.z;
    As[nxt][ac + 3][ar] = va0.w;
    As[nxt][ac + 0][ar + 64] = va1.x;
    As[nxt][ac + 1][ar + 64] = va1.y;
    As[nxt][ac + 2][ar + 64] = va1.z;
    As[nxt][ac + 3][ar + 64] = va1.w;
    // issue A global loads for tile t+2
    if (t + 2 < NT) {
      pa0 += FK;
      pa1 += FK;
      va0 = *(const float4*)pa0;
      va1 = *(const float4*)pa1;
    }

    // 16 k-steps, serial k-ascending per element (bit-exact order).
    // A from LDS; B consumed from pipeline slot, reload slot for g+2.
#pragma unroll
    for (int k = 0; k < FK; ++k) {
      const int sl = k & 1; // == (t*FK+k) & 1 since FK%2==0
      const float4 b0 = bq[sl][0];
      const float4 b1 = bq[sl][1];
      bq[sl][0] = *(const float4*)pb; // load for g+PD (always valid here)
      bq[sl][1] = *(const float4*)(pb + 64);
      pb += NMAT;
      const float4 a0 = *(const float4*)&As[cur][k][ty * 4];
      const float4 a1 = *(const float4*)&As[cur][k][64 + ty * 4];
      const float af[8] = {a0.x, a0.y, a0.z, a0.w, a1.x, a1.y, a1.z, a1.w};
      const float bf[8] = {b0.x, b0.y, b0.z, b0.w, b1.x, b1.y, b1.z, b1.w};
#pragma unroll
      for (int i = 0; i < 8; ++i)
#pragma unroll
        for (int j = 0; j < 8; ++j)
          acc[i][j] = fmaf(af[i], bf[j], acc[i][j]);
    }
    __syncthreads(); // buf[nxt] complete; buf[cur] free for reuse
  }

  // peeled last tile (t = NT-1): no A prefetch; B loads only while g+PD < 512
  {
    const int cur = (NT - 1) & 1;
#pragma unroll
    for (int k = 0; k < FK; ++k) {
      const int sl = k & 1;
      const float4 b0 = bq[sl][0];
      const float4 b1 = bq[sl][1];
      if (k < FK - PD) { // compile-time per unrolled k
        bq[sl][0] = *(const float4*)pb;
        bq[sl][1] = *(const float4*)(pb + 64);
        pb += NMAT;
      }
      const float4 a0 = *(const float4*)&As[cur][k][ty * 4];
      const float4 a1 = *(const float4*)&As[cur][k][64 + ty * 4];
      const float af[8] = {a0.x, a0.y, a0.z, a0.w, a1.x, a1.y, a1.z, a1.w};
      const float bf[8] = {b0.x, b0.y, b0.z, b0.w, b1.x, b1.y, b1.z, b1.w};
#pragma unroll
      for (int i = 0; i < 8; ++i)
#pragma unroll
        for (int j = 0; j < 8; ++j)
          acc[i][j] = fmaf(af[i], bf[j], acc[i][j]);
    }
  }

  // write raw chunk accumulator to partial slab z
  float* dst = Pm + (size_t)blockIdx.z * NMAT * NMAT;
#pragma unroll
  for (int i = 0; i < 8; ++i) {
    const int r = row0 + ((i < 4) ? (ty * 4 + i) : (64 + ty * 4 + (i - 4)));
#pragma unroll
    for (int jb = 0; jb < 2; ++jb) {
      const int c = col0 + ((jb == 0) ? (tx * 4) : (64 + tx * 4));
      float4 v;
      v.x = acc[i][jb * 4 + 0];
      v.y = acc[i][jb * 4 + 1];
      v.z = acc[i][jb * 4 + 2];
      v.w = acc[i][jb * 4 + 3];
      *(float4*)&dst[(size_t)r * NMAT + c] = v;
    }
  }
}

// ordered reduction: out = (((0+c0)+c1)+c2)+c3 [+ Addm], one fp32 rounding per
// add — bit-identical to the r11 tot-flush chain + epilogue add.
template <int DO_ADD>
__global__ __launch_bounds__(256) void reduce_k4(
    const float* __restrict__ Pm, const float* __restrict__ Addm,
    float* __restrict__ outp) {
  const size_t NN = (size_t)NMAT * NMAT;
  const size_t i = ((size_t)blockIdx.x * 256 + threadIdx.x) * 4;
  const float4 c0 = *(const float4*)&Pm[i];
  const float4 c1 = *(const float4*)&Pm[i + NN];
  const float4 c2 = *(const float4*)&Pm[i + 2 * NN];
  const float4 c3 = *(const float4*)&Pm[i + 3 * NN];
  float4 v;
  v.x = __fadd_rn(__fadd_rn(__fadd_rn(__fadd_rn(0.0f, c0.x), c1.x), c2.x), c3.x);
  v.y = __fadd_rn(__fadd_rn(__fadd_rn(__fadd_rn(0.0f, c0.y), c1.y), c2.y), c3.y);
  v.z = __fadd_rn(__fadd_rn(__fadd_rn(__fadd_rn(0.0f, c0.z), c1.z), c2.z), c3.z);
  v.w = __fadd_rn(__fadd_rn(__fadd_rn(__fadd_rn(0.0f, c0.w), c1.w), c2.w), c3.w);
  if (DO_ADD) {
    const float4 ad = *(const float4*)&Addm[i];
    v.x = __fadd_rn(v.x, ad.x);
    v.y = __fadd_rn(v.y, ad.y);
    v.z = __fadd_rn(v.z, ad.z);
    v.w = __fadd_rn(v.w, ad.w);
  }
  *(float4*)&outp[i] = v;
}

// ---------- fallback: r11 full-K kernel (used only if ws too small) ----------
constexpr int LDB = FN + 4;

template <int DO_ADD>
__global__ __launch_bounds__(256) void sgemm512(
    const float* __restrict__ Am, const float* __restrict__ Bm, float* Cm,
    const float* Addm) {
  __shared__ float As[FK][LDA];
  __shared__ float Bs[FK][LDB];
  const int tid = threadIdx.x;
  const int row0 = blockIdx.y * FM;
  const int col0 = blockIdx.x * FN;
  const int ty = tid >> 4;
  const int tx = tid & 15;
  const int ar = tid >> 2;
  const int ac = (tid & 3) * 4;
  const int bk = tid >> 5;
  const int bc = (tid & 31) * 4;

  float tot[8][8] = {};
  float acc[8][8] = {};
  float4 va0, va1, vb0, vb1;

  va0 = *(const float4*)&Am[(size_t)(row0 + ar) * NMAT + ac];
  va1 = *(const float4*)&Am[(size_t)(row0 + ar + 64) * NMAT + ac];
  vb0 = *(const float4*)&Bm[(size_t)bk * NMAT + col0 + bc];
  vb1 = *(const float4*)&Bm[(size_t)(bk + 8) * NMAT + col0 + bc];

  for (int k0 = 0; k0 < NMAT; k0 += FK) {
    __syncthreads();
    As[ac + 0][ar] = va0.x;
    As[ac + 1][ar] = va0.y;
    As[ac + 2][ar] = va0.z;
    As[ac + 3][ar] = va0.w;
    As[ac + 0][ar + 64] = va1.x;
    As[ac + 1][ar + 64] = va1.y;
    As[ac + 2][ar + 64] = va1.z;
    As[ac + 3][ar + 64] = va1.w;
    *(float4*)&Bs[bk][bc] = vb0;
    *(float4*)&Bs[bk + 8][bc] = vb1;
    __syncthreads();

    if (k0 + FK < NMAT) {
      const int kn = k0 + FK;
      va0 = *(const float4*)&Am[(size_t)(row0 + ar) * NMAT + kn + ac];
      va1 = *(const float4*)&Am[(size_t)(row0 + ar + 64) * NMAT + kn + ac];
      vb0 = *(const float4*)&Bm[(size_t)(kn + bk) * NMAT + col0 + bc];
      vb1 = *(const float4*)&Bm[(size_t)(kn + bk + 8) * NMAT + col0 + bc];
    }

#pragma unroll
    for (int k = 0; k < FK; ++k) {
      const float4 a0 = *(const float4*)&As[k][ty * 4];
      const float4 a1 = *(const float4*)&As[k][64 + ty * 4];
      const float4 b0 = *(const float4*)&Bs[k][tx * 4];
      const float4 b1 = *(const float4*)&Bs[k][64 + tx * 4];
      const float af[8] = {a0.x, a0.y, a0.z, a0.w, a1.x, a1.y, a1.z, a1.w};
      const float bf[8] = {b0.x, b0.y, b0.z, b0.w, b1.x, b1.y, b1.z, b1.w};
#pragma unroll
      for (int i = 0; i < 8; ++i)
#pragma unroll
        for (int j = 0; j < 8; ++j)
          acc[i][j] = fmaf(af[i], bf[j], acc[i][j]);
    }

    if (((k0 + FK) & 511) == 0) {
#pragma unroll
      for (int i = 0; i < 8; ++i)
#pragma unroll
        for (int j = 0; j < 8; ++j) {
          tot[i][j] = __fadd_rn(tot[i][j], acc[i][j]);
          acc[i][j] = 0.0f;
        }
    }
  }

#pragma unroll
  for (int i = 0; i < 8; ++i) {
    const int r = row0 + ((i < 4) ? (ty * 4 + i) : (64 + ty * 4 + (i - 4)));
#pragma unroll
    for (int jb = 0; jb < 2; ++jb) {
      const int c = col0 + ((jb == 0) ? (tx * 4) : (64 + tx * 4));
      const size_t idx = (size_t)r * NMAT + c;
      float4 v;
      v.x = tot[i][jb * 4 + 0];
      v.y = tot[i][jb * 4 + 1];
      v.z = tot[i][jb * 4 + 2];
      v.w = tot[i][jb * 4 + 3];
      if (DO_ADD) {
        const float4 ad = *(const float4*)&Addm[idx];
        v.x = __fadd_rn(v.x, ad.x);
        v.y = __fadd_rn(v.y, ad.y);
        v.z = __fadd_rn(v.z, ad.z);
        v.w = __fadd_rn(v.w, ad.w);
      }
      *(float4*)&Cm[idx] = v;
    }
  }
}

// out = t1 - (t2 + t3*t4/t5), each op one fp32 rounding, numpy eval order.
__global__ __launch_bounds__(256) void final_fp32(
    const float* __restrict__ t1, const float* __restrict__ t2,
    const float* t3, const float* __restrict__ t4,
    const float* __restrict__ t5, float* outp) {
  size_t i = (size_t)blockIdx.x * 256 + threadIdx.x;
  float num = __fmul_rn(t3[i], t4[i]);
  float q = __fdiv_rn(num, t5[i]);
  float s = __fadd_rn(t2[i], q);
  outp[i] = __fsub_rn(t1[i], s);
}

extern "C" void kernel_launch(void* const* d_in, const int* in_sizes, int n_in,
                              void* d_out, int out_size, void* d_ws,
                              size_t ws_size, hipStream_t stream) {
  const float* X1 = (const float*)d_in[0];
  const float* X2 = (const float*)d_in[1];
  float* out = (float*)d_out;

  const size_t NN = (size_t)NMAT * NMAT;
  const size_t M32 = NN * sizeof(float); // 16 MiB
  char* w = (char*)d_ws;
  float* fA  = (float*)(w + 0 * M32);
  float* fB  = (float*)(w + 1 * M32);
  float* fC  = (float*)(w + 2 * M32);
  float* fD  = (float*)(w + 3 * M32);
  float* fP  = (float*)(w + 4 * M32);
  float* fQ  = (float*)(w + 5 * M32);
  float* t2f = (float*)(w + 6 * M32);
  float* t4f = (float*)(w + 7 * M32);
  float* fT  = (float*)(w + 2 * M32); // reuse fC slab (dead after t3)
  float* t5f = (float*)(w + 3 * M32); // reuse fD slab (dead after t4)

  dim3 blk(256);
  dim3 ew((unsigned)(NN / 256));

  if (ws_size >= 12 * M32) {
    // split-K path: 12 slabs = 192 MiB (8 named + 4 partial chunks)
    float* Pk = (float*)(w + 8 * M32); // 4 x 16 MiB partials
    dim3 gsk(NMAT / FN, NMAT / FM, 4); // 16 x 16 x 4 = 1024 blocks
    dim3 gr((unsigned)(NN / (256 * 4)));

    auto gemm = [&](const float* A, const float* B, float* dst,
                    const float* add) {
      sgemm_chunk<<<gsk, blk, 0, stream>>>(A, B, Pk);
      if (add)
        reduce_k4<1><<<gr, blk, 0, stream>>>(Pk, add, dst);
      else
        reduce_k4<0><<<gr, blk, 0, stream>>>(Pk, nullptr, dst);
    };

    gemm(X1, X1, fA, nullptr);  // A  = X1@X1
    gemm(X1, X2, fB, nullptr);  // B  = X1@X2
    gemm(X2, fB, fC, nullptr);  // C  = X2@B
    gemm(X2, fA, fD, nullptr);  // D  = X2@A
    gemm(fC, fA, fP, nullptr);  // P  = C@A
    gemm(fD, fB, fQ, nullptr);  // Q  = D@B
    gemm(fB, fA, out, fC);      // t3 = B@A + C
    gemm(fD, X2, t4f, fP);      // t4 = D@X2 + P
    gemm(fA, X2, t2f, fB);      // t2 = A@X2 + B
    gemm(fP, fA, fT, nullptr);  // T  = P@A
    gemm(fQ, fA, t5f, fT);      // t5 = Q@A + T
    final_fp32<<<ew, blk, 0, stream>>>(fA, t2f, out, t4f, t5f, out);
  } else {
    // fallback: r11 path (128 MiB ws)
    dim3 grid(NMAT / FN, NMAT / FM);
    sgemm512<0><<<grid, blk, 0, stream>>>(X1, X1, fA, nullptr);
    sgemm512<0><<<grid, blk, 0, stream>>>(X1, X2, fB, nullptr);
    sgemm512<0><<<grid, blk, 0, stream>>>(X2, fB, fC, nullptr);
    sgemm512<0><<<grid, blk, 0, stream>>>(X2, fA, fD, nullptr);
    sgemm512<0><<<grid, blk, 0, stream>>>(fC, fA, fP, nullptr);
    sgemm512<0><<<grid, blk, 0, stream>>>(fD, fB, fQ, nullptr);
    sgemm512<1><<<grid, blk, 0, stream>>>(fB, fA, out, fC);
    sgemm512<1><<<grid, blk, 0, stream>>>(fD, X2, t4f, fP);
    sgemm512<1><<<grid, blk, 0, stream>>>(fA, X2, t2f, fB);
    sgemm512<0><<<grid, blk, 0, stream>>>(fP, fA, fT, nullptr);
    sgemm512<1><<<grid, blk, 0, stream>>>(fQ, fA, t5f, fT);
    final_fp32<<<ew, blk, 0, stream>>>(fA, t2f, out, t4f, t5f, out);
  }
}

// Round 16
// 2381.581 us; speedup vs baseline: 1.4514x; 1.3224x over previous
//
#include <hip/hip_runtime.h>

// Round 21: revert to r13's kernel (best measured: chunk 208.7us, total
// 2349.9us) + batch independent GEMMs. Evidence: r13 is ~90% of its LDS-pipe
// ceiling (885 LDS-cyc vs 2048 FMA-cyc per wave-tile -> ~58% duty cap;
// measured 52%); r15-r20 proved bigger tiles / B-from-global lose to the
// allocator or latency exposure. Remaining recoverable time = inter-dispatch
// drain/fill: 23 dependent launches. Change: pair independent GEMMs into one
// dispatch via z in [0,8) (z>>2 = which GEMM, z&3 = k-chunk): {A,B},{C,D},
// {P,Q},{t3,t2},{t4,T},{t5} -> 6 chunk + 6 reduce + final = 13 dispatches.
// Needs 8 partial slabs (ws >= 256MiB, guarded; 192MiB -> r13 plan).
// Bit-exact unchanged: serial k-ascending fp32 FMA, 512-k chunks, ordered
// (((0+c0)+c1)+c2)+c3 reduce + one Addm add -> absmax 0.0.

#define NMAT 2048

constexpr int FM = 128, FN = 128, FK = 16; // 256 threads, 8x8 out/thread
constexpr int LDA = FM + 4;                // 132 floats: 16B-multiple rows
constexpr int LDB = FN + 4;
constexpr int KCHUNK = 512;                // flush granularity (bit-exact)

// ---- paired split-K chunk kernel: z>>2 selects GEMM, z&3 selects k-chunk ----
__global__ __launch_bounds__(256) void sgemm_chunk2(
    const float* __restrict__ A0, const float* __restrict__ B0,
    const float* __restrict__ A1, const float* __restrict__ B1,
    float* __restrict__ Pm) {
  __shared__ float As[FK][LDA]; // [k][m]
  __shared__ float Bs[FK][LDB]; // [k][n]
  const int g = blockIdx.z >> 2; // which GEMM of the pair
  const float* __restrict__ Am = g ? A1 : A0;
  const float* __restrict__ Bm = g ? B1 : B0;
  const int kb = (blockIdx.z & 3) * KCHUNK;

  const int tid = threadIdx.x;
  const int row0 = blockIdx.y * FM;
  const int col0 = blockIdx.x * FN;
  const int ty = tid >> 4; // 0..15 -> rows {ty*4..+3, 64+ty*4..+3}
  const int tx = tid & 15; // 0..15 -> cols {tx*4..+3, 64+tx*4..+3}

  // staging indices (two passes: idx = tid, tid+256)
  const int ar = tid >> 2;      // 0..63   (second pass: +64)
  const int ac = (tid & 3) * 4; // 0,4,8,12
  const int bk = tid >> 5;      // 0..7    (second pass: +8)
  const int bc = (tid & 31) * 4;

  float acc[8][8] = {};
  float4 va0, va1, vb0, vb1;

  const float* pa0 = &Am[(size_t)(row0 + ar) * NMAT + kb + ac];
  const float* pa1 = pa0 + (size_t)64 * NMAT;
  const float* pb0 = &Bm[(size_t)(kb + bk) * NMAT + col0 + bc];
  const float* pb1 = pb0 + (size_t)8 * NMAT;

  // preload tile 0 into registers
  va0 = *(const float4*)pa0;
  va1 = *(const float4*)pa1;
  vb0 = *(const float4*)pb0;
  vb1 = *(const float4*)pb1;

#pragma unroll 1
  for (int t = 0; t < KCHUNK / FK; ++t) {
    __syncthreads(); // previous compute done -> safe to overwrite LDS
    As[ac + 0][ar] = va0.x;
    As[ac + 1][ar] = va0.y;
    As[ac + 2][ar] = va0.z;
    As[ac + 3][ar] = va0.w;
    As[ac + 0][ar + 64] = va1.x;
    As[ac + 1][ar + 64] = va1.y;
    As[ac + 2][ar + 64] = va1.z;
    As[ac + 3][ar + 64] = va1.w;
    *(float4*)&Bs[bk][bc] = vb0;
    *(float4*)&Bs[bk + 8][bc] = vb1;
    __syncthreads();

    // prefetch next tile into registers (lands during the FMA block)
    if (t + 1 < KCHUNK / FK) {
      pa0 += FK;
      pa1 += FK;
      pb0 += (size_t)FK * NMAT;
      pb1 += (size_t)FK * NMAT;
      va0 = *(const float4*)pa0;
      va1 = *(const float4*)pa1;
      vb0 = *(const float4*)pb0;
      vb1 = *(const float4*)pb1;
    }

    // compute: 16 k-steps, serial k-ascending per element (bit-exact order)
#pragma unroll
    for (int k = 0; k < FK; ++k) {
      const float4 a0 = *(const float4*)&As[k][ty * 4];
      const float4 a1 = *(const float4*)&As[k][64 + ty * 4];
      const float4 b0 = *(const float4*)&Bs[k][tx * 4];
      const float4 b1 = *(const float4*)&Bs[k][64 + tx * 4];
      const float af[8] = {a0.x, a0.y, a0.z, a0.w, a1.x, a1.y, a1.z, a1.w};
      const float bf[8] = {b0.x, b0.y, b0.z, b0.w, b1.x, b1.y, b1.z, b1.w};
#pragma unroll
      for (int i = 0; i < 8; ++i)
#pragma unroll
        for (int j = 0; j < 8; ++j)
          acc[i][j] = fmaf(af[i], bf[j], acc[i][j]);
    }
  }

  // write raw chunk accumulator to partial slab blockIdx.z
  float* dst = Pm + (size_t)blockIdx.z * NMAT * NMAT;
#pragma unroll
  for (int i = 0; i < 8; ++i) {
    const int r = row0 + ((i < 4) ? (ty * 4 + i) : (64 + ty * 4 + (i - 4)));
#pragma unroll
    for (int jb = 0; jb < 2; ++jb) {
      const int c = col0 + ((jb == 0) ? (tx * 4) : (64 + tx * 4));
      float4 v;
      v.x = acc[i][jb * 4 + 0];
      v.y = acc[i][jb * 4 + 1];
      v.z = acc[i][jb * 4 + 2];
      v.w = acc[i][jb * 4 + 3];
      *(float4*)&dst[(size_t)r * NMAT + c] = v;
    }
  }
}

// paired ordered reduction: first half of grid -> out0 from slabs 0..3
// (+Ad0), second half -> out1 from slabs 4..7 (+Ad1). Chain bit-identical to
// r11's tot-flush + epilogue add. g is uniform per block (NN/4 % 256 == 0).
__global__ __launch_bounds__(256) void reduce_k4_2(
    const float* __restrict__ Pm, const float* __restrict__ Ad0,
    const float* __restrict__ Ad1, float* __restrict__ o0,
    float* __restrict__ o1) {
  const size_t NN = (size_t)NMAT * NMAT;
  const size_t Q = NN / 4; // float4 slots per output
  const size_t gi = (size_t)blockIdx.x * 256 + threadIdx.x;
  const int g = gi >= Q;
  const size_t i = (gi - (g ? Q : 0)) * 4;
  const float* P = Pm + (g ? 4 * NN : 0);
  const float* ad = g ? Ad1 : Ad0;
  float* op = g ? o1 : o0;

  const float4 c0 = *(const float4*)&P[i];
  const float4 c1 = *(const float4*)&P[i + NN];
  const float4 c2 = *(const float4*)&P[i + 2 * NN];
  const float4 c3 = *(const float4*)&P[i + 3 * NN];
  float4 v;
  v.x = __fadd_rn(__fadd_rn(__fadd_rn(__fadd_rn(0.0f, c0.x), c1.x), c2.x), c3.x);
  v.y = __fadd_rn(__fadd_rn(__fadd_rn(__fadd_rn(0.0f, c0.y), c1.y), c2.y), c3.y);
  v.z = __fadd_rn(__fadd_rn(__fadd_rn(__fadd_rn(0.0f, c0.z), c1.z), c2.z), c3.z);
  v.w = __fadd_rn(__fadd_rn(__fadd_rn(__fadd_rn(0.0f, c0.w), c1.w), c2.w), c3.w);
  if (ad) {
    const float4 a = *(const float4*)&ad[i];
    v.x = __fadd_rn(v.x, a.x);
    v.y = __fadd_rn(v.y, a.y);
    v.z = __fadd_rn(v.z, a.z);
    v.w = __fadd_rn(v.w, a.w);
  }
  *(float4*)&op[i] = v;
}

// single ordered reduction (fallback path + final t5)
template <int DO_ADD>
__global__ __launch_bounds__(256) void reduce_k4(
    const float* __restrict__ Pm, const float* __restrict__ Addm,
    float* __restrict__ outp) {
  const size_t NN = (size_t)NMAT * NMAT;
  const size_t i = ((size_t)blockIdx.x * 256 + threadIdx.x) * 4;
  const float4 c0 = *(const float4*)&Pm[i];
  const float4 c1 = *(const float4*)&Pm[i + NN];
  const float4 c2 = *(const float4*)&Pm[i + 2 * NN];
  const float4 c3 = *(const float4*)&Pm[i + 3 * NN];
  float4 v;
  v.x = __fadd_rn(__fadd_rn(__fadd_rn(__fadd_rn(0.0f, c0.x), c1.x), c2.x), c3.x);
  v.y = __fadd_rn(__fadd_rn(__fadd_rn(__fadd_rn(0.0f, c0.y), c1.y), c2.y), c3.y);
  v.z = __fadd_rn(__fadd_rn(__fadd_rn(__fadd_rn(0.0f, c0.z), c1.z), c2.z), c3.z);
  v.w = __fadd_rn(__fadd_rn(__fadd_rn(__fadd_rn(0.0f, c0.w), c1.w), c2.w), c3.w);
  if (DO_ADD) {
    const float4 ad = *(const float4*)&Addm[i];
    v.x = __fadd_rn(v.x, ad.x);
    v.y = __fadd_rn(v.y, ad.y);
    v.z = __fadd_rn(v.z, ad.z);
    v.w = __fadd_rn(v.w, ad.w);
  }
  *(float4*)&outp[i] = v;
}

// out = t1 - (t2 + t3*t4/t5), each op one fp32 rounding, numpy eval order.
__global__ __launch_bounds__(256) void final_fp32(
    const float* __restrict__ t1, const float* __restrict__ t2,
    const float* t3, const float* __restrict__ t4,
    const float* __restrict__ t5, float* outp) {
  size_t i = (size_t)blockIdx.x * 256 + threadIdx.x;
  float num = __fmul_rn(t3[i], t4[i]);
  float q = __fdiv_rn(num, t5[i]);
  float s = __fadd_rn(t2[i], q);
  outp[i] = __fsub_rn(t1[i], s);
}

extern "C" void kernel_launch(void* const* d_in, const int* in_sizes, int n_in,
                              void* d_out, int out_size, void* d_ws,
                              size_t ws_size, hipStream_t stream) {
  const float* X1 = (const float*)d_in[0];
  const float* X2 = (const float*)d_in[1];
  float* out = (float*)d_out;

  const size_t NN = (size_t)NMAT * NMAT;
  const size_t M32 = NN * sizeof(float); // 16 MiB
  char* w = (char*)d_ws;
  float* fA  = (float*)(w + 0 * M32);
  float* fB  = (float*)(w + 1 * M32);
  float* fC  = (float*)(w + 2 * M32);
  float* fD  = (float*)(w + 3 * M32);
  float* fP  = (float*)(w + 4 * M32);
  float* fQ  = (float*)(w + 5 * M32);
  float* t2f = (float*)(w + 6 * M32);
  float* t4f = (float*)(w + 7 * M32);
  float* fT  = (float*)(w + 2 * M32); // reuse fC slab (dead after t3-reduce)
  float* t5f = (float*)(w + 3 * M32); // reuse fD slab (dead after t4-chunk)

  dim3 blk(256);
  dim3 ew((unsigned)(NN / 256));
  dim3 gr1((unsigned)(NN / 1024));

  if (ws_size >= 16 * M32) {
    // paired plan: 8 named + 8 partial slabs = 256 MiB; 13 dispatches
    float* Pk = (float*)(w + 8 * M32);
    dim3 g8(NMAT / FN, NMAT / FM, 8); // 2048 blocks (2 GEMMs x 4 chunks)
    dim3 g4(NMAT / FN, NMAT / FM, 4);
    dim3 gr2((unsigned)(2 * NN / 1024));

    // 1: A = X1@X1 | B = X1@X2
    sgemm_chunk2<<<g8, blk, 0, stream>>>(X1, X1, X1, X2, Pk);
    reduce_k4_2<<<gr2, blk, 0, stream>>>(Pk, nullptr, nullptr, fA, fB);
    // 2: C = X2@B | D = X2@A
    sgemm_chunk2<<<g8, blk, 0, stream>>>(X2, fB, X2, fA, Pk);
    reduce_k4_2<<<gr2, blk, 0, stream>>>(Pk, nullptr, nullptr, fC, fD);
    // 3: P = C@A | Q = D@B
    sgemm_chunk2<<<g8, blk, 0, stream>>>(fC, fA, fD, fB, Pk);
    reduce_k4_2<<<gr2, blk, 0, stream>>>(Pk, nullptr, nullptr, fP, fQ);
    // 4: t3 = B@A + C  | t2 = A@X2 + B
    sgemm_chunk2<<<g8, blk, 0, stream>>>(fB, fA, fA, X2, Pk);
    reduce_k4_2<<<gr2, blk, 0, stream>>>(Pk, fC, fB, out, t2f);
    // 5: t4 = D@X2 + P | T = P@A        (fT overwrites fC — dead after 4)
    sgemm_chunk2<<<g8, blk, 0, stream>>>(fD, X2, fP, fA, Pk);
    reduce_k4_2<<<gr2, blk, 0, stream>>>(Pk, fP, nullptr, t4f, fT);
    // 6: t5 = Q@A + T                   (t5f overwrites fD — dead after 5)
    sgemm_chunk2<<<g4, blk, 0, stream>>>(fQ, fA, fQ, fA, Pk);
    reduce_k4<1><<<gr1, blk, 0, stream>>>(Pk, fT, t5f);

    final_fp32<<<ew, blk, 0, stream>>>(fA, t2f, out, t4f, t5f, out);
  } else if (ws_size >= 12 * M32) {
    // r13 plan: 8 named + 4 partial slabs = 192 MiB; 23 dispatches
    float* Pk = (float*)(w + 8 * M32);
    dim3 g4(NMAT / FN, NMAT / FM, 4);

    auto gemm = [&](const float* A, const float* B, float* dst,
                    const float* add) {
      sgemm_chunk2<<<g4, blk, 0, stream>>>(A, B, A, B, Pk);
      if (add)
        reduce_k4<1><<<gr1, blk, 0, stream>>>(Pk, add, dst);
      else
        reduce_k4<0><<<gr1, blk, 0, stream>>>(Pk, nullptr, dst);
    };

    gemm(X1, X1, fA, nullptr);  // A  = X1@X1
    gemm(X1, X2, fB, nullptr);  // B  = X1@X2
    gemm(X2, fB, fC, nullptr);  // C  = X2@B
    gemm(X2, fA, fD, nullptr);  // D  = X2@A
    gemm(fC, fA, fP, nullptr);  // P  = C@A
    gemm(fD, fB, fQ, nullptr);  // Q  = D@B
    gemm(fB, fA, out, fC);      // t3 = B@A + C
    gemm(fD, X2, t4f, fP);      // t4 = D@X2 + P
    gemm(fA, X2, t2f, fB);      // t2 = A@X2 + B
    gemm(fP, fA, fT, nullptr);  // T  = P@A
    gemm(fQ, fA, t5f, fT);      // t5 = Q@A + T
    final_fp32<<<ew, blk, 0, stream>>>(fA, t2f, out, t4f, t5f, out);
  }
}